// Round 2
// baseline (375.788 us; speedup 1.0000x reference)
//
#include <hip/hip_runtime.h>
#include <cstdint>
#include <cstddef>

#define B_   2
#define N_   6
#define FD_  128
#define DIM_ 128
#define H_   64
#define W_   176
#define P_   (H_*W_)      // 11264
#define IMGW 704.0
#define IMGH 256.0

struct __align__(16) Samp { float wx, wy; int o00, o01; int o10, o11; int valid, pad; };

__device__ __forceinline__ float wave_sum(float v) {
#pragma unroll
  for (int off = 32; off > 0; off >>= 1) v += __shfl_xor(v, off, 64);
  return v;
}

// ---------------- Kernel A: fp64 homography -> sample descriptors; BN fold ----------------
__global__ __launch_bounds__(256) void uv_kernel(const float* __restrict__ I_src, const float* __restrict__ I_tar_inv,
                           const float* __restrict__ E, const float* __restrict__ dis,
                           const float* __restrict__ nrm,
                           const float* __restrict__ bn_g, const float* __restrict__ bn_b,
                           const float* __restrict__ bn_m, const float* __restrict__ bn_v,
                           Samp* __restrict__ samp, float* __restrict__ bns, float* __restrict__ bnb) {
  int bn = blockIdx.x;            // 0..11
  int bb = bn / N_;
  if (bn == 0 && threadIdx.x < FD_) {
    int t = threadIdx.x;
    float inv = 1.0f / sqrtf(bn_v[t] + 1e-5f);
    float sc = bn_g[t] * inv;
    bns[t] = sc;
    bnb[t] = bn_b[t] - bn_m[t] * sc;
  }
  // all threads redundantly compute the 3x3 homography in fp64
  const float* Ep = E + bn * 16;
  double R[9], T[3];
#pragma unroll
  for (int i = 0; i < 3; ++i) {
#pragma unroll
    for (int j = 0; j < 3; ++j) R[i*3+j] = (double)Ep[i*4+j];
    T[i] = (double)Ep[i*4+3];
  }
  double dd = (double)dis[bb];
  double M[9];
#pragma unroll
  for (int i = 0; i < 3; ++i)
#pragma unroll
    for (int j = 0; j < 3; ++j)
      M[i*3+j] = R[i*3+j] - T[i] * (double)nrm[bb*3+j] / dd;
  const float* Is = I_src + bn * 9;
  double A[9];
#pragma unroll
  for (int i = 0; i < 3; ++i)
#pragma unroll
    for (int j = 0; j < 3; ++j)
      A[i*3+j] = (double)Is[i*3+0]*M[0+j] + (double)Is[i*3+1]*M[3+j] + (double)Is[i*3+2]*M[6+j];
  const float* It = I_tar_inv + bb * 9;
  double Hm[9];
#pragma unroll
  for (int i = 0; i < 3; ++i)
#pragma unroll
    for (int j = 0; j < 3; ++j)
      Hm[i*3+j] = A[i*3+0]*(double)It[0+j] + A[i*3+1]*(double)It[3+j] + A[i*3+2]*(double)It[6+j];

  const double dx = 1.0 / (double)(W_ - 1);
  const double dy = 1.0 / (double)(H_ - 1);
  for (int p = threadIdx.x; p < P_; p += 256) {
    int ii = p / W_;
    int jj = p - ii * W_;
    double xs = (jj == W_ - 1) ? 1.0 : (double)jj * dx;   // np.linspace exact endpoint
    double ys = (ii == H_ - 1) ? 1.0 : (double)ii * dy;
    double px = xs * IMGW;
    double py = ys * IMGH;
    double hx = Hm[0]*px + Hm[1]*py + Hm[2];
    double hy = Hm[3]*px + Hm[4]*py + Hm[5];
    double hz = Hm[6]*px + Hm[7]*py + Hm[8];
    double u = ((hx / hz) / IMGW) * (double)W_;
    double v = ((hy / hz) / IMGH) * (double)H_;
    double x0 = floor(u), y0 = floor(v);
    bool valid = (u >= 0.0) && (u <= (double)(W_ - 1)) && (v >= 0.0) && (v <= (double)(H_ - 1));
    int x0i = min(max((int)x0, 0), W_ - 1);
    int x1i = min(x0i + 1, W_ - 1);
    int y0i = min(max((int)y0, 0), H_ - 1);
    int y1i = min(y0i + 1, H_ - 1);
    Samp s;
    s.wx = (float)(u - x0);
    s.wy = (float)(v - y0);
    s.o00 = (y0i * W_ + x0i) * DIM_;
    s.o01 = (y0i * W_ + x1i) * DIM_;
    s.o10 = (y1i * W_ + x0i) * DIM_;
    s.o11 = (y1i * W_ + x1i) * DIM_;
    s.valid = valid ? 1 : 0;
    s.pad = 0;
    samp[(size_t)bn * P_ + p] = s;
  }
}

// ---------------- Kernel B: BN+ReLU+1x1 conv GEMM -> val_t[bn][p][o] ----------------
__global__ __launch_bounds__(256) void conv_kernel(const float* __restrict__ feature,
    const float* __restrict__ conv_w, const float* __restrict__ bns_g, const float* __restrict__ bnb_g,
    float* __restrict__ val_t) {
  __shared__ float wsm[DIM_ * FD_];   // 64 KB: W[o][c]
  __shared__ float bns_s[FD_], bnb_s[FD_];
  int t = threadIdx.x;
  {
    const float4* src = (const float4*)conv_w;
    float4* dst = (float4*)wsm;
#pragma unroll
    for (int k = 0; k < 16; ++k) dst[k*256 + t] = src[k*256 + t];
  }
  if (t < FD_) { bns_s[t] = bns_g[t]; bnb_s[t] = bnb_g[t]; }
  __syncthreads();

  int bn = blockIdx.y;            // 0..11
  int p0 = blockIdx.x * 64;       // pixel tile
  int pp = t & 15;                // 16 pixel-quads
  int oo = t >> 4;                // 16 o-groups of 8
  int ob = oo * 8;
  const float* fb = feature + (size_t)bn * FD_ * P_ + p0 + pp * 4;

  float acc[8][4];
#pragma unroll
  for (int j = 0; j < 8; ++j)
#pragma unroll
    for (int q = 0; q < 4; ++q) acc[j][q] = 0.f;

  for (int c4 = 0; c4 < 32; ++c4) {
    float4 xv[4];
#pragma unroll
    for (int cc = 0; cc < 4; ++cc) {
      int c = c4 * 4 + cc;
      float4 x = *(const float4*)(fb + (size_t)c * P_);
      float s = bns_s[c], o = bnb_s[c];
      x.x = fmaxf(x.x * s + o, 0.f);
      x.y = fmaxf(x.y * s + o, 0.f);
      x.z = fmaxf(x.z * s + o, 0.f);
      x.w = fmaxf(x.w * s + o, 0.f);
      xv[cc] = x;
    }
#pragma unroll
    for (int j = 0; j < 8; ++j) {
      float4 wv = *(const float4*)&wsm[(ob + j) * FD_ + c4 * 4];
      acc[j][0] += wv.x*xv[0].x + wv.y*xv[1].x + wv.z*xv[2].x + wv.w*xv[3].x;
      acc[j][1] += wv.x*xv[0].y + wv.y*xv[1].y + wv.z*xv[2].y + wv.w*xv[3].y;
      acc[j][2] += wv.x*xv[0].z + wv.y*xv[1].z + wv.z*xv[2].z + wv.w*xv[3].z;
      acc[j][3] += wv.x*xv[0].w + wv.y*xv[1].w + wv.z*xv[2].w + wv.w*xv[3].w;
    }
  }
  float* vb = val_t + ((size_t)bn * P_ + p0 + pp * 4) * DIM_ + ob;
#pragma unroll
  for (int q = 0; q < 4; ++q) {
    float4 a = make_float4(acc[0][q], acc[1][q], acc[2][q], acc[3][q]);
    float4 b = make_float4(acc[4][q], acc[5][q], acc[6][q], acc[7][q]);
    *(float4*)(vb + (size_t)q * DIM_)     = a;
    *(float4*)(vb + (size_t)q * DIM_ + 4) = b;
  }
}

// ---------------- Kernel C: warp-per-point bilinear attention + LN1 ----------------
__global__ __launch_bounds__(256) void attn_kernel(const float* __restrict__ val_t,
    const Samp* __restrict__ samp,
    const float* __restrict__ ln1g, const float* __restrict__ ln1b,
    float* __restrict__ zln) {
  int lane = threadIdx.x & 63;
  int wv = threadIdx.x >> 6;
  int pt = blockIdx.x * 4 + wv;
  if (pt >= B_ * P_) return;
  int bb = pt / P_;
  int p = pt - bb * P_;
  int d0 = lane << 1;

  float2 q = *(const float2*)(val_t + ((size_t)(bb * N_) * P_ + p) * DIM_ + d0);
  float qss = wave_sum(q.x * q.x + q.y * q.y);
  float qinv = 1.0f / fmaxf(sqrtf(qss), 1e-12f);
  float qn0 = q.x * qinv, qn1 = q.y * qinv;

  float dots[N_], vs0[N_], vs1[N_];
#pragma unroll
  for (int n = 0; n < N_; ++n) {
    Samp s = samp[(size_t)(bb * N_ + n) * P_ + p];
    const float* base = val_t + (size_t)(bb * N_ + n) * P_ * DIM_ + d0;
    float2 g00 = *(const float2*)(base + s.o00);
    float2 g01 = *(const float2*)(base + s.o01);
    float2 g10 = *(const float2*)(base + s.o10);
    float2 g11 = *(const float2*)(base + s.o11);
    float wx = s.wx, wy = s.wy;
    float w00 = (1.0f - wx) * (1.0f - wy), w01 = wx * (1.0f - wy);
    float w10 = (1.0f - wx) * wy,          w11 = wx * wy;
    float v0 = g00.x*w00 + g01.x*w01 + g10.x*w10 + g11.x*w11;
    float v1 = g00.y*w00 + g01.y*w01 + g10.y*w10 + g11.y*w11;
    float ss = wave_sum(v0 * v0 + v1 * v1);
    float kinv = 1.0f / fmaxf(sqrtf(ss), 1e-12f);
    float dt = wave_sum(qn0 * (v0 * kinv) + qn1 * (v1 * kinv));
    dots[n] = s.valid ? dt : 0.0f;
    vs0[n] = v0; vs1[n] = v1;
  }
  float mx = dots[0];
#pragma unroll
  for (int n = 1; n < N_; ++n) mx = fmaxf(mx, dots[n]);
  float es[N_], den = 0.f;
#pragma unroll
  for (int n = 0; n < N_; ++n) { es[n] = expf(dots[n] - mx); den += es[n]; }
  float dinv = 1.0f / den;
  float z0 = q.x, z1 = q.y;
#pragma unroll
  for (int n = 0; n < N_; ++n) { float a = es[n] * dinv; z0 += a * vs0[n]; z1 += a * vs1[n]; }
  // LN1
  float mean = wave_sum(z0 + z1) * (1.0f / DIM_);
  float c0 = z0 - mean, c1 = z1 - mean;
  float var = wave_sum(c0 * c0 + c1 * c1) * (1.0f / DIM_);
  float rstd = rsqrtf(var + 1e-5f);
  float o0 = c0 * rstd * ln1g[d0]     + ln1b[d0];
  float o1 = c1 * rstd * ln1g[d0 + 1] + ln1b[d0 + 1];
  *(float2*)(zln + (size_t)pt * DIM_ + d0) = make_float2(o0, o1);
}

// ---------------- Kernel D: MLP + LN2 + transposed output ----------------
__global__ __launch_bounds__(256) void mlp_kernel(const float* __restrict__ zln,
    const float* __restrict__ w1, const float* __restrict__ b1,
    const float* __restrict__ w2, const float* __restrict__ b2,
    const float* __restrict__ ln2g, const float* __restrict__ ln2b,
    float* __restrict__ out) {
  __shared__ float zl[32 * 132];    // zln tile, padded
  __shared__ float hd[32 * 256];    // hdn tile; reused later as zo[32*133]
  int t = threadIdx.x;
  int row0 = blockIdx.x * 32;

  // load zln tile
#pragma unroll
  for (int k = 0; k < 4; ++k) {
    int idx4 = k * 256 + t;
    int r = idx4 >> 5, c4 = idx4 & 31;
    float4 v = *(const float4*)(zln + (size_t)(row0 + r) * DIM_ + c4 * 4);
    *(float4*)&zl[r * 132 + c4 * 4] = v;
  }
  __syncthreads();

  // matvec1: hdn[r][t] for j = t (0..255)
  float acc[32];
#pragma unroll
  for (int r = 0; r < 32; ++r) acc[r] = 0.f;
  for (int d4 = 0; d4 < 32; ++d4) {
    float w_0 = w1[(d4*4 + 0) * 256 + t];
    float w_1 = w1[(d4*4 + 1) * 256 + t];
    float w_2 = w1[(d4*4 + 2) * 256 + t];
    float w_3 = w1[(d4*4 + 3) * 256 + t];
#pragma unroll
    for (int r = 0; r < 32; ++r) {
      float4 z4 = *(float4*)&zl[r * 132 + d4 * 4];
      acc[r] += z4.x * w_0 + z4.y * w_1 + z4.z * w_2 + z4.w * w_3;
    }
  }
  float bb1 = b1[t];
#pragma unroll
  for (int r = 0; r < 32; ++r) {
    float hv = acc[r] + bb1;
    hd[r * 256 + t] = 0.5f * hv * (1.0f + erff(hv * 0.70710678118654752f));
  }
  __syncthreads();

  // matvec2: d = t&127, two row-halves
  int d = t & 127, rh = t >> 7;
  float acc2[16];
#pragma unroll
  for (int k = 0; k < 16; ++k) acc2[k] = 0.f;
  for (int j4 = 0; j4 < 64; ++j4) {
    float w_0 = w2[(j4*4 + 0) * 128 + d];
    float w_1 = w2[(j4*4 + 1) * 128 + d];
    float w_2 = w2[(j4*4 + 2) * 128 + d];
    float w_3 = w2[(j4*4 + 3) * 128 + d];
#pragma unroll
    for (int k = 0; k < 16; ++k) {
      int r = rh * 16 + k;
      float4 h4 = *(float4*)&hd[r * 256 + j4 * 4];
      acc2[k] += h4.x * w_0 + h4.y * w_1 + h4.z * w_2 + h4.w * w_3;
    }
  }
  float bb2 = b2[d];
  float z2v[16];
#pragma unroll
  for (int k = 0; k < 16; ++k) {
    int r = rh * 16 + k;
    z2v[k] = acc2[k] + bb2 + zl[r * 132 + d];
  }
  __syncthreads();              // everyone done reading hd
  float* zo = hd;               // reuse as zo[32][133]
#pragma unroll
  for (int k = 0; k < 16; ++k) {
    int r = rh * 16 + k;
    zo[r * 133 + d] = z2v[k];
  }
  __syncthreads();

  // LN2: 8 threads per row
  int rr = t >> 3, part = t & 7;
  float s = 0.f;
#pragma unroll
  for (int k = 0; k < 16; ++k) s += zo[rr * 133 + part + 8 * k];
  s += __shfl_xor(s, 1, 8); s += __shfl_xor(s, 2, 8); s += __shfl_xor(s, 4, 8);
  float mean = s * (1.0f / 128.0f);
  float v = 0.f;
#pragma unroll
  for (int k = 0; k < 16; ++k) { float dl = zo[rr * 133 + part + 8 * k] - mean; v += dl * dl; }
  v += __shfl_xor(v, 1, 8); v += __shfl_xor(v, 2, 8); v += __shfl_xor(v, 4, 8);
  float rstd = rsqrtf(v * (1.0f / 128.0f) + 1e-5f);
#pragma unroll
  for (int k = 0; k < 16; ++k) {
    int dd = part + 8 * k;
    float val = (zo[rr * 133 + dd] - mean) * rstd * ln2g[dd] + ln2b[dd];
    zo[rr * 133 + dd] = val;
  }
  __syncthreads();

  // transposed write: out[b][d][p]
  int bb = row0 / P_;
  int p0 = row0 - bb * P_;
#pragma unroll
  for (int it = 0; it < 16; ++it) {
    int dd = it * 8 + (t >> 5);
    int r = t & 31;
    out[(size_t)bb * DIM_ * P_ + (size_t)dd * P_ + p0 + r] = zo[r * 133 + dd];
  }
}

extern "C" void kernel_launch(void* const* d_in, const int* in_sizes, int n_in,
                              void* d_out, int out_size, void* d_ws, size_t ws_size,
                              hipStream_t stream) {
  const float* feature = (const float*)d_in[0];
  const float* I_src   = (const float*)d_in[1];
  const float* I_tar   = (const float*)d_in[2];
  const float* E       = (const float*)d_in[3];
  const float* dis     = (const float*)d_in[4];
  const float* nrm     = (const float*)d_in[5];
  const float* conv_w  = (const float*)d_in[6];
  const float* bn_g    = (const float*)d_in[7];
  const float* bn_b    = (const float*)d_in[8];
  const float* bn_m    = (const float*)d_in[9];
  const float* bn_v    = (const float*)d_in[10];
  const float* ln1g    = (const float*)d_in[11];
  const float* ln1b    = (const float*)d_in[12];
  const float* ln2g    = (const float*)d_in[13];
  const float* ln2b    = (const float*)d_in[14];
  const float* w1      = (const float*)d_in[15];
  const float* b1      = (const float*)d_in[16];
  const float* w2      = (const float*)d_in[17];
  const float* b2      = (const float*)d_in[18];
  float* out = (float*)d_out;

  float* wsf   = (float*)d_ws;
  float* bns   = wsf;                 // 128
  float* bnb   = wsf + 128;           // 128
  float* val_t = wsf + 256;           // B*N*P*DIM = 17,301,504 floats
  float* zln   = val_t + (size_t)B_ * N_ * P_ * DIM_;  // B*P*DIM floats
  Samp*  samp  = (Samp*)(zln + (size_t)B_ * P_ * DIM_); // 12*P structs (32B each)

  hipLaunchKernelGGL(uv_kernel, dim3(B_ * N_), dim3(256), 0, stream,
                     I_src, I_tar, E, dis, nrm, bn_g, bn_b, bn_m, bn_v, samp, bns, bnb);
  hipLaunchKernelGGL(conv_kernel, dim3(P_ / 64, B_ * N_), dim3(256), 0, stream,
                     feature, conv_w, bns, bnb, val_t);
  hipLaunchKernelGGL(attn_kernel, dim3(B_ * P_ / 4), dim3(256), 0, stream,
                     val_t, samp, ln1g, ln1b, zln);
  hipLaunchKernelGGL(mlp_kernel, dim3(B_ * P_ / 32), dim3(256), 0, stream,
                     zln, w1, b1, w2, b2, ln2g, ln2b, out);
}

// Round 3
// 288.050 us; speedup vs baseline: 1.3046x; 1.3046x over previous
//
#include <hip/hip_runtime.h>
#include <cstdint>
#include <cstddef>

#define B_   2
#define N_   6
#define FD_  128
#define DIM_ 128
#define H_   64
#define W_   176
#define P_   (H_*W_)      // 11264
#define IMGW 704.0
#define IMGH 256.0

struct __align__(16) Samp { float wx, wy; int o00, o01; int o10, o11; int valid, pad; };

typedef __attribute__((ext_vector_type(8))) short short8;
typedef __attribute__((ext_vector_type(4))) float f32x4;

__device__ __forceinline__ float wave_sum(float v) {
#pragma unroll
  for (int off = 32; off > 0; off >>= 1) v += __shfl_xor(v, off, 64);
  return v;
}

__device__ __forceinline__ unsigned short f2bf(float f) {
  unsigned int u = __float_as_uint(f);
  unsigned int r = (u + 0x7fffu + ((u >> 16) & 1u)) >> 16;
  return (unsigned short)r;
}
__device__ __forceinline__ float bf2f(unsigned short s) {
  return __uint_as_float(((unsigned int)s) << 16);
}

// ---------------- Kernel A: fp64 homography -> sample descriptors; BN fold ----------------
__global__ __launch_bounds__(256) void uv_kernel(const float* __restrict__ I_src, const float* __restrict__ I_tar_inv,
                           const float* __restrict__ E, const float* __restrict__ dis,
                           const float* __restrict__ nrm,
                           const float* __restrict__ bn_g, const float* __restrict__ bn_b,
                           const float* __restrict__ bn_m, const float* __restrict__ bn_v,
                           Samp* __restrict__ samp, float* __restrict__ bns, float* __restrict__ bnb) {
  int bn = blockIdx.x;            // 0..11
  int bb = bn / N_;
  if (bn == 0 && threadIdx.x < FD_) {
    int t = threadIdx.x;
    float inv = 1.0f / sqrtf(bn_v[t] + 1e-5f);
    float sc = bn_g[t] * inv;
    bns[t] = sc;
    bnb[t] = bn_b[t] - bn_m[t] * sc;
  }
  const float* Ep = E + bn * 16;
  double R[9], T[3];
#pragma unroll
  for (int i = 0; i < 3; ++i) {
#pragma unroll
    for (int j = 0; j < 3; ++j) R[i*3+j] = (double)Ep[i*4+j];
    T[i] = (double)Ep[i*4+3];
  }
  double dd = (double)dis[bb];
  double M[9];
#pragma unroll
  for (int i = 0; i < 3; ++i)
#pragma unroll
    for (int j = 0; j < 3; ++j)
      M[i*3+j] = R[i*3+j] - T[i] * (double)nrm[bb*3+j] / dd;
  const float* Is = I_src + bn * 9;
  double A[9];
#pragma unroll
  for (int i = 0; i < 3; ++i)
#pragma unroll
    for (int j = 0; j < 3; ++j)
      A[i*3+j] = (double)Is[i*3+0]*M[0+j] + (double)Is[i*3+1]*M[3+j] + (double)Is[i*3+2]*M[6+j];
  const float* It = I_tar_inv + bb * 9;
  double Hm[9];
#pragma unroll
  for (int i = 0; i < 3; ++i)
#pragma unroll
    for (int j = 0; j < 3; ++j)
      Hm[i*3+j] = A[i*3+0]*(double)It[0+j] + A[i*3+1]*(double)It[3+j] + A[i*3+2]*(double)It[6+j];

  const double dx = 1.0 / (double)(W_ - 1);
  const double dy = 1.0 / (double)(H_ - 1);
  for (int p = threadIdx.x; p < P_; p += 256) {
    int ii = p / W_;
    int jj = p - ii * W_;
    double xs = (jj == W_ - 1) ? 1.0 : (double)jj * dx;   // np.linspace exact endpoint
    double ys = (ii == H_ - 1) ? 1.0 : (double)ii * dy;
    double px = xs * IMGW;
    double py = ys * IMGH;
    double hx = Hm[0]*px + Hm[1]*py + Hm[2];
    double hy = Hm[3]*px + Hm[4]*py + Hm[5];
    double hz = Hm[6]*px + Hm[7]*py + Hm[8];
    double u = ((hx / hz) / IMGW) * (double)W_;
    double v = ((hy / hz) / IMGH) * (double)H_;
    double x0 = floor(u), y0 = floor(v);
    bool valid = (u >= 0.0) && (u <= (double)(W_ - 1)) && (v >= 0.0) && (v <= (double)(H_ - 1));
    int x0i = min(max((int)x0, 0), W_ - 1);
    int x1i = min(x0i + 1, W_ - 1);
    int y0i = min(max((int)y0, 0), H_ - 1);
    int y1i = min(y0i + 1, H_ - 1);
    Samp s;
    s.wx = (float)(u - x0);
    s.wy = (float)(v - y0);
    s.o00 = (y0i * W_ + x0i) * DIM_;
    s.o01 = (y0i * W_ + x1i) * DIM_;
    s.o10 = (y1i * W_ + x0i) * DIM_;
    s.o11 = (y1i * W_ + x1i) * DIM_;
    s.valid = valid ? 1 : 0;
    s.pad = 0;
    samp[(size_t)bn * P_ + p] = s;
  }
}

// ---------------- Kernel B: BN+ReLU+1x1 conv as bf16 MFMA (hi/lo split X) -> val_t[bn][p][o] ----------------
// X staged transposed [c][p] stride 66 shorts (quads land on disjoint banks);
// W staged [o][c] stride 136 shorts. A-frags register-cached; 1 ds_read_b128 : 2 MFMA inner loop.
__global__ __launch_bounds__(256) void conv_kernel(const float* __restrict__ feature,
    const float* __restrict__ conv_w, const float* __restrict__ bns_g, const float* __restrict__ bnb_g,
    float* __restrict__ val_t) {
  __shared__ __align__(16) short w_lds[128 * 136];  // 34816 B
  __shared__ __align__(16) short xhi[128 * 66];     // 16896 B
  __shared__ __align__(16) short xlo[128 * 66];     // 16896 B
  __shared__ float bns_s[FD_], bnb_s[FD_];
  int t = threadIdx.x;

  // stage W (bf16): w_lds[o][c]
#pragma unroll
  for (int k = 0; k < 16; ++k) {
    int f4 = t + 256 * k;          // 0..4095 float4s
    int o  = f4 >> 5;              // 32 float4 per o-row
    int c4 = (f4 & 31) * 4;
    float4 w = *(const float4*)(conv_w + (size_t)f4 * 4);
    short* dst = &w_lds[o * 136 + c4];
    dst[0] = (short)f2bf(w.x); dst[1] = (short)f2bf(w.y);
    dst[2] = (short)f2bf(w.z); dst[3] = (short)f2bf(w.w);
  }
  if (t < FD_) { bns_s[t] = bns_g[t]; bnb_s[t] = bnb_g[t]; }
  __syncthreads();

  int bn = blockIdx.y;            // 0..11
  int p0 = blockIdx.x * 64;       // pixel tile
  const float* fb = feature + (size_t)bn * FD_ * P_ + p0;

  // stage X: BN+ReLU, hi/lo bf16 split, transposed to [c][p]
#pragma unroll
  for (int k = 0; k < 8; ++k) {
    int f4 = t + 256 * k;          // 0..2047 ; 16 float4 per c-row
    int c  = f4 >> 4;
    int pq = (f4 & 15) * 4;
    float4 x = *(const float4*)(fb + (size_t)c * P_ + pq);
    float s = bns_s[c], o = bnb_s[c];
    float v0 = fmaxf(x.x * s + o, 0.f);
    float v1 = fmaxf(x.y * s + o, 0.f);
    float v2 = fmaxf(x.z * s + o, 0.f);
    float v3 = fmaxf(x.w * s + o, 0.f);
    unsigned short h0 = f2bf(v0), h1 = f2bf(v1), h2 = f2bf(v2), h3 = f2bf(v3);
    unsigned short l0 = f2bf(v0 - bf2f(h0)), l1 = f2bf(v1 - bf2f(h1));
    unsigned short l2 = f2bf(v2 - bf2f(h2)), l3 = f2bf(v3 - bf2f(h3));
    short* dh = &xhi[c * 66 + pq];
    short* dl = &xlo[c * 66 + pq];
    dh[0] = (short)h0; dh[1] = (short)h1; dh[2] = (short)h2; dh[3] = (short)h3;
    dl[0] = (short)l0; dl[1] = (short)l1; dl[2] = (short)l2; dl[3] = (short)l3;
  }
  __syncthreads();

  // compute: 4 waves, each 16 pixels x 128 outputs
  int lane = t & 63, wv = t >> 6;
  int m = lane & 15, quad = lane >> 4;
  int pw = wv * 16;

  short8 Ah[4], Al[4];
#pragma unroll
  for (int ks = 0; ks < 4; ++ks) {
#pragma unroll
    for (int j = 0; j < 8; ++j) {
      int c = ks * 32 + quad * 8 + j;
      Ah[ks][j] = xhi[c * 66 + pw + m];
      Al[ks][j] = xlo[c * 66 + pw + m];
    }
  }

  f32x4 acc[8];
#pragma unroll
  for (int ot = 0; ot < 8; ++ot) {
    f32x4 a = {0.f, 0.f, 0.f, 0.f};
#pragma unroll
    for (int ks = 0; ks < 4; ++ks) {
      short8 Bv = *(const short8*)&w_lds[(ot * 16 + m) * 136 + ks * 32 + quad * 8];
      a = __builtin_amdgcn_mfma_f32_16x16x32_bf16(Ah[ks], Bv, a, 0, 0, 0);
      a = __builtin_amdgcn_mfma_f32_16x16x32_bf16(Al[ks], Bv, a, 0, 0, 0);
    }
    acc[ot] = a;
  }

  // epilogue: C row = quad*4+reg (pixel), col = m (output dim)
  float* vb = val_t + ((size_t)bn * P_ + p0 + pw + quad * 4) * DIM_ + m;
#pragma unroll
  for (int ot = 0; ot < 8; ++ot)
#pragma unroll
    for (int r = 0; r < 4; ++r)
      vb[(size_t)r * DIM_ + ot * 16] = acc[ot][r];
}

// ---------------- Kernel C: warp-per-point bilinear attention + LN1 ----------------
__global__ __launch_bounds__(256) void attn_kernel(const float* __restrict__ val_t,
    const Samp* __restrict__ samp,
    const float* __restrict__ ln1g, const float* __restrict__ ln1b,
    float* __restrict__ zln) {
  int lane = threadIdx.x & 63;
  int wv = threadIdx.x >> 6;
  int pt = blockIdx.x * 4 + wv;
  if (pt >= B_ * P_) return;
  int bb = pt / P_;
  int p = pt - bb * P_;
  int d0 = lane << 1;

  float2 q = *(const float2*)(val_t + ((size_t)(bb * N_) * P_ + p) * DIM_ + d0);
  float qss = wave_sum(q.x * q.x + q.y * q.y);
  float qinv = 1.0f / fmaxf(sqrtf(qss), 1e-12f);
  float qn0 = q.x * qinv, qn1 = q.y * qinv;

  float dots[N_], vs0[N_], vs1[N_];
#pragma unroll
  for (int n = 0; n < N_; ++n) {
    Samp s = samp[(size_t)(bb * N_ + n) * P_ + p];
    const float* base = val_t + (size_t)(bb * N_ + n) * P_ * DIM_ + d0;
    float2 g00 = *(const float2*)(base + s.o00);
    float2 g01 = *(const float2*)(base + s.o01);
    float2 g10 = *(const float2*)(base + s.o10);
    float2 g11 = *(const float2*)(base + s.o11);
    float wx = s.wx, wy = s.wy;
    float w00 = (1.0f - wx) * (1.0f - wy), w01 = wx * (1.0f - wy);
    float w10 = (1.0f - wx) * wy,          w11 = wx * wy;
    float v0 = g00.x*w00 + g01.x*w01 + g10.x*w10 + g11.x*w11;
    float v1 = g00.y*w00 + g01.y*w01 + g10.y*w10 + g11.y*w11;
    float ss = wave_sum(v0 * v0 + v1 * v1);
    float kinv = 1.0f / fmaxf(sqrtf(ss), 1e-12f);
    float dt = wave_sum(qn0 * (v0 * kinv) + qn1 * (v1 * kinv));
    dots[n] = s.valid ? dt : 0.0f;
    vs0[n] = v0; vs1[n] = v1;
  }
  float mx = dots[0];
#pragma unroll
  for (int n = 1; n < N_; ++n) mx = fmaxf(mx, dots[n]);
  float es[N_], den = 0.f;
#pragma unroll
  for (int n = 0; n < N_; ++n) { es[n] = expf(dots[n] - mx); den += es[n]; }
  float dinv = 1.0f / den;
  float z0 = q.x, z1 = q.y;
#pragma unroll
  for (int n = 0; n < N_; ++n) { float a = es[n] * dinv; z0 += a * vs0[n]; z1 += a * vs1[n]; }
  // LN1
  float mean = wave_sum(z0 + z1) * (1.0f / DIM_);
  float c0 = z0 - mean, c1 = z1 - mean;
  float var = wave_sum(c0 * c0 + c1 * c1) * (1.0f / DIM_);
  float rstd = rsqrtf(var + 1e-5f);
  float o0 = c0 * rstd * ln1g[d0]     + ln1b[d0];
  float o1 = c1 * rstd * ln1g[d0 + 1] + ln1b[d0 + 1];
  *(float2*)(zln + (size_t)pt * DIM_ + d0) = make_float2(o0, o1);
}

// ---------------- Kernel D: MLP + LN2 + transposed output ----------------
__global__ __launch_bounds__(256) void mlp_kernel(const float* __restrict__ zln,
    const float* __restrict__ w1, const float* __restrict__ b1,
    const float* __restrict__ w2, const float* __restrict__ b2,
    const float* __restrict__ ln2g, const float* __restrict__ ln2b,
    float* __restrict__ out) {
  __shared__ float zl[32 * 132];    // zln tile, padded
  __shared__ float hd[32 * 256];    // hdn tile; reused later as zo[32*133]
  int t = threadIdx.x;
  int row0 = blockIdx.x * 32;

  // load zln tile
#pragma unroll
  for (int k = 0; k < 4; ++k) {
    int idx4 = k * 256 + t;
    int r = idx4 >> 5, c4 = idx4 & 31;
    float4 v = *(const float4*)(zln + (size_t)(row0 + r) * DIM_ + c4 * 4);
    *(float4*)&zl[r * 132 + c4 * 4] = v;
  }
  __syncthreads();

  // matvec1: hdn[r][t] for j = t (0..255)
  float acc[32];
#pragma unroll
  for (int r = 0; r < 32; ++r) acc[r] = 0.f;
  for (int d4 = 0; d4 < 32; ++d4) {
    float w_0 = w1[(d4*4 + 0) * 256 + t];
    float w_1 = w1[(d4*4 + 1) * 256 + t];
    float w_2 = w1[(d4*4 + 2) * 256 + t];
    float w_3 = w1[(d4*4 + 3) * 256 + t];
#pragma unroll
    for (int r = 0; r < 32; ++r) {
      float4 z4 = *(float4*)&zl[r * 132 + d4 * 4];
      acc[r] += z4.x * w_0 + z4.y * w_1 + z4.z * w_2 + z4.w * w_3;
    }
  }
  float bb1 = b1[t];
#pragma unroll
  for (int r = 0; r < 32; ++r) {
    float hv = acc[r] + bb1;
    hd[r * 256 + t] = 0.5f * hv * (1.0f + erff(hv * 0.70710678118654752f));
  }
  __syncthreads();

  // matvec2: d = t&127, two row-halves
  int d = t & 127, rh = t >> 7;
  float acc2[16];
#pragma unroll
  for (int k = 0; k < 16; ++k) acc2[k] = 0.f;
  for (int j4 = 0; j4 < 64; ++j4) {
    float w_0 = w2[(j4*4 + 0) * 128 + d];
    float w_1 = w2[(j4*4 + 1) * 128 + d];
    float w_2 = w2[(j4*4 + 2) * 128 + d];
    float w_3 = w2[(j4*4 + 3) * 128 + d];
#pragma unroll
    for (int k = 0; k < 16; ++k) {
      int r = rh * 16 + k;
      float4 h4 = *(float4*)&hd[r * 256 + j4 * 4];
      acc2[k] += h4.x * w_0 + h4.y * w_1 + h4.z * w_2 + h4.w * w_3;
    }
  }
  float bb2 = b2[d];
  float z2v[16];
#pragma unroll
  for (int k = 0; k < 16; ++k) {
    int r = rh * 16 + k;
    z2v[k] = acc2[k] + bb2 + zl[r * 132 + d];
  }
  __syncthreads();              // everyone done reading hd
  float* zo = hd;               // reuse as zo[32][133]
#pragma unroll
  for (int k = 0; k < 16; ++k) {
    int r = rh * 16 + k;
    zo[r * 133 + d] = z2v[k];
  }
  __syncthreads();

  // LN2: 8 threads per row
  int rr = t >> 3, part = t & 7;
  float s = 0.f;
#pragma unroll
  for (int k = 0; k < 16; ++k) s += zo[rr * 133 + part + 8 * k];
  s += __shfl_xor(s, 1, 8); s += __shfl_xor(s, 2, 8); s += __shfl_xor(s, 4, 8);
  float mean = s * (1.0f / 128.0f);
  float v = 0.f;
#pragma unroll
  for (int k = 0; k < 16; ++k) { float dl = zo[rr * 133 + part + 8 * k] - mean; v += dl * dl; }
  v += __shfl_xor(v, 1, 8); v += __shfl_xor(v, 2, 8); v += __shfl_xor(v, 4, 8);
  float rstd = rsqrtf(v * (1.0f / 128.0f) + 1e-5f);
#pragma unroll
  for (int k = 0; k < 16; ++k) {
    int dd = part + 8 * k;
    float val = (zo[rr * 133 + dd] - mean) * rstd * ln2g[dd] + ln2b[dd];
    zo[rr * 133 + dd] = val;
  }
  __syncthreads();

  // transposed write: out[b][d][p]
  int bb = row0 / P_;
  int p0 = row0 - bb * P_;
#pragma unroll
  for (int it = 0; it < 16; ++it) {
    int dd = it * 8 + (t >> 5);
    int r = t & 31;
    out[(size_t)bb * DIM_ * P_ + (size_t)dd * P_ + p0 + r] = zo[r * 133 + dd];
  }
}

extern "C" void kernel_launch(void* const* d_in, const int* in_sizes, int n_in,
                              void* d_out, int out_size, void* d_ws, size_t ws_size,
                              hipStream_t stream) {
  const float* feature = (const float*)d_in[0];
  const float* I_src   = (const float*)d_in[1];
  const float* I_tar   = (const float*)d_in[2];
  const float* E       = (const float*)d_in[3];
  const float* dis     = (const float*)d_in[4];
  const float* nrm     = (const float*)d_in[5];
  const float* conv_w  = (const float*)d_in[6];
  const float* bn_g    = (const float*)d_in[7];
  const float* bn_b    = (const float*)d_in[8];
  const float* bn_m    = (const float*)d_in[9];
  const float* bn_v    = (const float*)d_in[10];
  const float* ln1g    = (const float*)d_in[11];
  const float* ln1b    = (const float*)d_in[12];
  const float* ln2g    = (const float*)d_in[13];
  const float* ln2b    = (const float*)d_in[14];
  const float* w1      = (const float*)d_in[15];
  const float* b1      = (const float*)d_in[16];
  const float* w2      = (const float*)d_in[17];
  const float* b2      = (const float*)d_in[18];
  float* out = (float*)d_out;

  float* wsf   = (float*)d_ws;
  float* bns   = wsf;                 // 128
  float* bnb   = wsf + 128;           // 128
  float* val_t = wsf + 256;           // B*N*P*DIM = 17,301,504 floats
  float* zln   = val_t + (size_t)B_ * N_ * P_ * DIM_;  // B*P*DIM floats
  Samp*  samp  = (Samp*)(zln + (size_t)B_ * P_ * DIM_); // 12*P structs (32B each)

  hipLaunchKernelGGL(uv_kernel, dim3(B_ * N_), dim3(256), 0, stream,
                     I_src, I_tar, E, dis, nrm, bn_g, bn_b, bn_m, bn_v, samp, bns, bnb);
  hipLaunchKernelGGL(conv_kernel, dim3(P_ / 64, B_ * N_), dim3(256), 0, stream,
                     feature, conv_w, bns, bnb, val_t);
  hipLaunchKernelGGL(attn_kernel, dim3(B_ * P_ / 4), dim3(256), 0, stream,
                     val_t, samp, ln1g, ln1b, zln);
  hipLaunchKernelGGL(mlp_kernel, dim3(B_ * P_ / 32), dim3(256), 0, stream,
                     zln, w1, b1, w2, b2, ln2g, ln2b, out);
}

// Round 4
// 268.283 us; speedup vs baseline: 1.4007x; 1.0737x over previous
//
#include <hip/hip_runtime.h>
#include <cstdint>
#include <cstddef>

#define B_   2
#define N_   6
#define FD_  128
#define DIM_ 128
#define H_   64
#define W_   176
#define P_   (H_*W_)      // 11264
#define IMGW 704.0
#define IMGH 256.0

struct __align__(16) Samp { float wx, wy; int o00, o01; int o10, o11; int valid, pad; };

typedef __attribute__((ext_vector_type(8))) short short8;
typedef __attribute__((ext_vector_type(4))) float f32x4;

__device__ __forceinline__ float wave_sum(float v) {
#pragma unroll
  for (int off = 32; off > 0; off >>= 1) v += __shfl_xor(v, off, 64);
  return v;
}

__device__ __forceinline__ unsigned short f2bf(float f) {
  unsigned int u = __float_as_uint(f);
  unsigned int r = (u + 0x7fffu + ((u >> 16) & 1u)) >> 16;
  return (unsigned short)r;
}
__device__ __forceinline__ float bf2f(unsigned short s) {
  return __uint_as_float(((unsigned int)s) << 16);
}

// ---------------- Kernel A: fp64 homography -> sample descriptors; BN fold ----------------
__global__ __launch_bounds__(256) void uv_kernel(const float* __restrict__ I_src, const float* __restrict__ I_tar_inv,
                           const float* __restrict__ E, const float* __restrict__ dis,
                           const float* __restrict__ nrm,
                           const float* __restrict__ bn_g, const float* __restrict__ bn_b,
                           const float* __restrict__ bn_m, const float* __restrict__ bn_v,
                           Samp* __restrict__ samp, float* __restrict__ bns, float* __restrict__ bnb) {
  int bn = blockIdx.x;            // 0..11
  int bb = bn / N_;
  if (bn == 0 && threadIdx.x < FD_) {
    int t = threadIdx.x;
    float inv = 1.0f / sqrtf(bn_v[t] + 1e-5f);
    float sc = bn_g[t] * inv;
    bns[t] = sc;
    bnb[t] = bn_b[t] - bn_m[t] * sc;
  }
  const float* Ep = E + bn * 16;
  double R[9], T[3];
#pragma unroll
  for (int i = 0; i < 3; ++i) {
#pragma unroll
    for (int j = 0; j < 3; ++j) R[i*3+j] = (double)Ep[i*4+j];
    T[i] = (double)Ep[i*4+3];
  }
  double dd = (double)dis[bb];
  double M[9];
#pragma unroll
  for (int i = 0; i < 3; ++i)
#pragma unroll
    for (int j = 0; j < 3; ++j)
      M[i*3+j] = R[i*3+j] - T[i] * (double)nrm[bb*3+j] / dd;
  const float* Is = I_src + bn * 9;
  double A[9];
#pragma unroll
  for (int i = 0; i < 3; ++i)
#pragma unroll
    for (int j = 0; j < 3; ++j)
      A[i*3+j] = (double)Is[i*3+0]*M[0+j] + (double)Is[i*3+1]*M[3+j] + (double)Is[i*3+2]*M[6+j];
  const float* It = I_tar_inv + bb * 9;
  double Hm[9];
#pragma unroll
  for (int i = 0; i < 3; ++i)
#pragma unroll
    for (int j = 0; j < 3; ++j)
      Hm[i*3+j] = A[i*3+0]*(double)It[0+j] + A[i*3+1]*(double)It[3+j] + A[i*3+2]*(double)It[6+j];

  const double dx = 1.0 / (double)(W_ - 1);
  const double dy = 1.0 / (double)(H_ - 1);
  for (int p = threadIdx.x; p < P_; p += 256) {
    int ii = p / W_;
    int jj = p - ii * W_;
    double xs = (jj == W_ - 1) ? 1.0 : (double)jj * dx;   // np.linspace exact endpoint
    double ys = (ii == H_ - 1) ? 1.0 : (double)ii * dy;
    double px = xs * IMGW;
    double py = ys * IMGH;
    double hx = Hm[0]*px + Hm[1]*py + Hm[2];
    double hy = Hm[3]*px + Hm[4]*py + Hm[5];
    double hz = Hm[6]*px + Hm[7]*py + Hm[8];
    double u = ((hx / hz) / IMGW) * (double)W_;
    double v = ((hy / hz) / IMGH) * (double)H_;
    double x0 = floor(u), y0 = floor(v);
    bool valid = (u >= 0.0) && (u <= (double)(W_ - 1)) && (v >= 0.0) && (v <= (double)(H_ - 1));
    int x0i = min(max((int)x0, 0), W_ - 1);
    int x1i = min(x0i + 1, W_ - 1);
    int y0i = min(max((int)y0, 0), H_ - 1);
    int y1i = min(y0i + 1, H_ - 1);
    Samp s;
    s.wx = (float)(u - x0);
    s.wy = (float)(v - y0);
    s.o00 = (y0i * W_ + x0i) * DIM_;
    s.o01 = (y0i * W_ + x1i) * DIM_;
    s.o10 = (y1i * W_ + x0i) * DIM_;
    s.o11 = (y1i * W_ + x1i) * DIM_;
    s.valid = valid ? 1 : 0;
    s.pad = 0;
    samp[(size_t)bn * P_ + p] = s;
  }
}

// ---------------- Kernel A2: pre-swizzle MLP weights into MFMA B-frag layout (hi/lo bf16) ----------------
// w1 (128x256): frag id f = nt*4+ks (nt 0..15, ks 0..3); lane l: n = nt*16+(l&15), k = ks*32+(l>>4)*8+j
// w2 (256x128): frag id g = nt*8+ks (nt 0..7, ks 0..7)
__global__ __launch_bounds__(64) void wprep_kernel(const float* __restrict__ w1, const float* __restrict__ w2,
    short* __restrict__ w1h, short* __restrict__ w1l,
    short* __restrict__ w2h, short* __restrict__ w2l) {
  int l = threadIdx.x;
  int f = blockIdx.x;     // 0..127
  if (f < 64) {
    int nt = f >> 2, ks = f & 3;
    int n = nt * 16 + (l & 15);
    int kb = ks * 32 + (l >> 4) * 8;
#pragma unroll
    for (int j = 0; j < 8; ++j) {
      float v = w1[(size_t)(kb + j) * 256 + n];
      unsigned short h = f2bf(v);
      w1h[((size_t)f * 64 + l) * 8 + j] = (short)h;
      w1l[((size_t)f * 64 + l) * 8 + j] = (short)f2bf(v - bf2f(h));
    }
  } else {
    int g = f - 64;
    int nt = g >> 3, ks = g & 7;
    int n = nt * 16 + (l & 15);
    int kb = ks * 32 + (l >> 4) * 8;
#pragma unroll
    for (int j = 0; j < 8; ++j) {
      float v = w2[(size_t)(kb + j) * 128 + n];
      unsigned short h = f2bf(v);
      w2h[((size_t)g * 64 + l) * 8 + j] = (short)h;
      w2l[((size_t)g * 64 + l) * 8 + j] = (short)f2bf(v - bf2f(h));
    }
  }
}

// ---------------- Kernel B: BN+ReLU+1x1 conv as bf16 MFMA (hi/lo split X) -> val_t[bn][p][o] ----------------
__global__ __launch_bounds__(256) void conv_kernel(const float* __restrict__ feature,
    const float* __restrict__ conv_w, const float* __restrict__ bns_g, const float* __restrict__ bnb_g,
    float* __restrict__ val_t) {
  __shared__ __align__(16) short w_lds[128 * 136];  // 34816 B
  __shared__ __align__(16) short xhi[128 * 66];     // 16896 B
  __shared__ __align__(16) short xlo[128 * 66];     // 16896 B
  __shared__ float bns_s[FD_], bnb_s[FD_];
  int t = threadIdx.x;

  // stage W (bf16): w_lds[o][c]
#pragma unroll
  for (int k = 0; k < 16; ++k) {
    int f4 = t + 256 * k;          // 0..4095 float4s
    int o  = f4 >> 5;              // 32 float4 per o-row
    int c4 = (f4 & 31) * 4;
    float4 w = *(const float4*)(conv_w + (size_t)f4 * 4);
    short* dst = &w_lds[o * 136 + c4];
    dst[0] = (short)f2bf(w.x); dst[1] = (short)f2bf(w.y);
    dst[2] = (short)f2bf(w.z); dst[3] = (short)f2bf(w.w);
  }
  if (t < FD_) { bns_s[t] = bns_g[t]; bnb_s[t] = bnb_g[t]; }
  __syncthreads();

  int bn = blockIdx.y;            // 0..11
  int p0 = blockIdx.x * 64;       // pixel tile
  const float* fb = feature + (size_t)bn * FD_ * P_ + p0;

  // stage X: BN+ReLU, hi/lo bf16 split, transposed to [c][p]
#pragma unroll
  for (int k = 0; k < 8; ++k) {
    int f4 = t + 256 * k;          // 0..2047 ; 16 float4 per c-row
    int c  = f4 >> 4;
    int pq = (f4 & 15) * 4;
    float4 x = *(const float4*)(fb + (size_t)c * P_ + pq);
    float s = bns_s[c], o = bnb_s[c];
    float v0 = fmaxf(x.x * s + o, 0.f);
    float v1 = fmaxf(x.y * s + o, 0.f);
    float v2 = fmaxf(x.z * s + o, 0.f);
    float v3 = fmaxf(x.w * s + o, 0.f);
    unsigned short h0 = f2bf(v0), h1 = f2bf(v1), h2 = f2bf(v2), h3 = f2bf(v3);
    unsigned short l0 = f2bf(v0 - bf2f(h0)), l1 = f2bf(v1 - bf2f(h1));
    unsigned short l2 = f2bf(v2 - bf2f(h2)), l3 = f2bf(v3 - bf2f(h3));
    short* dh = &xhi[c * 66 + pq];
    short* dl = &xlo[c * 66 + pq];
    dh[0] = (short)h0; dh[1] = (short)h1; dh[2] = (short)h2; dh[3] = (short)h3;
    dl[0] = (short)l0; dl[1] = (short)l1; dl[2] = (short)l2; dl[3] = (short)l3;
  }
  __syncthreads();

  // compute: 4 waves, each 16 pixels x 128 outputs
  int lane = t & 63, wv = t >> 6;
  int m = lane & 15, quad = lane >> 4;
  int pw = wv * 16;

  short8 Ah[4], Al[4];
#pragma unroll
  for (int ks = 0; ks < 4; ++ks) {
#pragma unroll
    for (int j = 0; j < 8; ++j) {
      int c = ks * 32 + quad * 8 + j;
      Ah[ks][j] = xhi[c * 66 + pw + m];
      Al[ks][j] = xlo[c * 66 + pw + m];
    }
  }

  f32x4 acc[8];
#pragma unroll
  for (int ot = 0; ot < 8; ++ot) {
    f32x4 a = {0.f, 0.f, 0.f, 0.f};
#pragma unroll
    for (int ks = 0; ks < 4; ++ks) {
      short8 Bv = *(const short8*)&w_lds[(ot * 16 + m) * 136 + ks * 32 + quad * 8];
      a = __builtin_amdgcn_mfma_f32_16x16x32_bf16(Ah[ks], Bv, a, 0, 0, 0);
      a = __builtin_amdgcn_mfma_f32_16x16x32_bf16(Al[ks], Bv, a, 0, 0, 0);
    }
    acc[ot] = a;
  }

  // epilogue: C row = quad*4+reg (pixel), col = m (output dim)
  float* vb = val_t + ((size_t)bn * P_ + p0 + pw + quad * 4) * DIM_ + m;
#pragma unroll
  for (int ot = 0; ot < 8; ++ot)
#pragma unroll
    for (int r = 0; r < 4; ++r)
      vb[(size_t)r * DIM_ + ot * 16] = acc[ot][r];
}

// ---------------- Kernel C: warp-per-point bilinear attention + LN1 ----------------
__global__ __launch_bounds__(256) void attn_kernel(const float* __restrict__ val_t,
    const Samp* __restrict__ samp,
    const float* __restrict__ ln1g, const float* __restrict__ ln1b,
    float* __restrict__ zln) {
  int lane = threadIdx.x & 63;
  int wv = threadIdx.x >> 6;
  int pt = blockIdx.x * 4 + wv;
  if (pt >= B_ * P_) return;
  int bb = pt / P_;
  int p = pt - bb * P_;
  int d0 = lane << 1;

  float2 q = *(const float2*)(val_t + ((size_t)(bb * N_) * P_ + p) * DIM_ + d0);
  float qss = wave_sum(q.x * q.x + q.y * q.y);
  float qinv = 1.0f / fmaxf(sqrtf(qss), 1e-12f);
  float qn0 = q.x * qinv, qn1 = q.y * qinv;

  float dots[N_], vs0[N_], vs1[N_];
#pragma unroll
  for (int n = 0; n < N_; ++n) {
    Samp s = samp[(size_t)(bb * N_ + n) * P_ + p];
    const float* base = val_t + (size_t)(bb * N_ + n) * P_ * DIM_ + d0;
    float2 g00 = *(const float2*)(base + s.o00);
    float2 g01 = *(const float2*)(base + s.o01);
    float2 g10 = *(const float2*)(base + s.o10);
    float2 g11 = *(const float2*)(base + s.o11);
    float wx = s.wx, wy = s.wy;
    float w00 = (1.0f - wx) * (1.0f - wy), w01 = wx * (1.0f - wy);
    float w10 = (1.0f - wx) * wy,          w11 = wx * wy;
    float v0 = g00.x*w00 + g01.x*w01 + g10.x*w10 + g11.x*w11;
    float v1 = g00.y*w00 + g01.y*w01 + g10.y*w10 + g11.y*w11;
    float ss = wave_sum(v0 * v0 + v1 * v1);
    float kinv = 1.0f / fmaxf(sqrtf(ss), 1e-12f);
    float dt = wave_sum(qn0 * (v0 * kinv) + qn1 * (v1 * kinv));
    dots[n] = s.valid ? dt : 0.0f;
    vs0[n] = v0; vs1[n] = v1;
  }
  float mx = dots[0];
#pragma unroll
  for (int n = 1; n < N_; ++n) mx = fmaxf(mx, dots[n]);
  float es[N_], den = 0.f;
#pragma unroll
  for (int n = 0; n < N_; ++n) { es[n] = expf(dots[n] - mx); den += es[n]; }
  float dinv = 1.0f / den;
  float z0 = q.x, z1 = q.y;
#pragma unroll
  for (int n = 0; n < N_; ++n) { float a = es[n] * dinv; z0 += a * vs0[n]; z1 += a * vs1[n]; }
  // LN1
  float mean = wave_sum(z0 + z1) * (1.0f / DIM_);
  float c0 = z0 - mean, c1 = z1 - mean;
  float var = wave_sum(c0 * c0 + c1 * c1) * (1.0f / DIM_);
  float rstd = rsqrtf(var + 1e-5f);
  float o0 = c0 * rstd * ln1g[d0]     + ln1b[d0];
  float o1 = c1 * rstd * ln1g[d0 + 1] + ln1b[d0 + 1];
  *(float2*)(zln + (size_t)pt * DIM_ + d0) = make_float2(o0, o1);
}

// ---------------- Kernel D: MLP via bf16 MFMA (3-term hi/lo) + LN2 + transposed output ----------------
// Block: 256 thr = 4 waves, 64 pixels. Per wave: 16 pixels.
// GEMM1: zl A-frags (hi/lo) x w1 frags (hi/lo, global) -> GELU -> hdn LDS (bf16 hi/lo, A-layout).
// GEMM2: hdn A-frags x w2 frags -> +bias +residual -> LN2 (quad shuffles) -> LDS transpose -> coalesced store.
__global__ __launch_bounds__(256) void mlp_kernel(const float* __restrict__ zln,
    const short* __restrict__ w1h, const short* __restrict__ w1l,
    const short* __restrict__ w2h, const short* __restrict__ w2l,
    const float* __restrict__ b1, const float* __restrict__ b2,
    const float* __restrict__ ln2g, const float* __restrict__ ln2b,
    float* __restrict__ out) {
  __shared__ __align__(16) float zl[64 * 132];          // 33792 B
  __shared__ __align__(16) short hdnh[4][16 * 264];     // 33792 B (per-wave 16x264)
  __shared__ __align__(16) short hdnl[4][16 * 264];     // 33792 B
  int t = threadIdx.x;
  int row0 = blockIdx.x * 64;

  // load zl tile (64 x 128, stride 132)
#pragma unroll
  for (int k = 0; k < 8; ++k) {
    int idx = t + 256 * k;        // 0..2047 float4s
    int r = idx >> 5, c4 = (idx & 31) * 4;
    *(float4*)&zl[r * 132 + c4] = *(const float4*)(zln + (size_t)(row0 + r) * DIM_ + c4);
  }
  __syncthreads();

  int lane = t & 63, wv = t >> 6, m = lane & 15, quad = lane >> 4;
  int pw = wv * 16;

  // A1 frags: row m of this wave's 16 pixels, hi/lo split
  short8 A1h[4], A1l[4];
#pragma unroll
  for (int ks = 0; ks < 4; ++ks) {
    const float* zr = &zl[(pw + m) * 132 + ks * 32 + quad * 8];
#pragma unroll
    for (int j = 0; j < 8; ++j) {
      float v = zr[j];
      unsigned short h = f2bf(v);
      A1h[ks][j] = (short)h;
      A1l[ks][j] = (short)f2bf(v - bf2f(h));
    }
  }

  float b1v[16];
#pragma unroll
  for (int nt = 0; nt < 16; ++nt) b1v[nt] = b1[nt * 16 + m];

  short* hh = &hdnh[wv][0];
  short* hl = &hdnl[wv][0];

  // GEMM1 + GELU + hdn store (wave-local LDS region, no barrier needed)
#pragma unroll
  for (int nt = 0; nt < 16; ++nt) {
    f32x4 a = {0.f, 0.f, 0.f, 0.f};
#pragma unroll
    for (int ks = 0; ks < 4; ++ks) {
      short8 Bh = *(const short8*)(w1h + ((size_t)(nt * 4 + ks) * 64 + lane) * 8);
      short8 Bl = *(const short8*)(w1l + ((size_t)(nt * 4 + ks) * 64 + lane) * 8);
      a = __builtin_amdgcn_mfma_f32_16x16x32_bf16(A1h[ks], Bh, a, 0, 0, 0);
      a = __builtin_amdgcn_mfma_f32_16x16x32_bf16(A1l[ks], Bh, a, 0, 0, 0);
      a = __builtin_amdgcn_mfma_f32_16x16x32_bf16(A1h[ks], Bl, a, 0, 0, 0);
    }
#pragma unroll
    for (int r = 0; r < 4; ++r) {
      float hv = a[r] + b1v[nt];
      float g = 0.5f * hv * (1.0f + erff(hv * 0.70710678118654752f));
      unsigned short gh = f2bf(g);
      int addr = (quad * 4 + r) * 264 + nt * 16 + m;
      hh[addr] = (short)gh;
      hl[addr] = (short)f2bf(g - bf2f(gh));
    }
  }

  // GEMM2: A from hdn (own wave region), B from global w2 frags
  f32x4 acc2[8];
#pragma unroll
  for (int nt = 0; nt < 8; ++nt) acc2[nt] = (f32x4){0.f, 0.f, 0.f, 0.f};
#pragma unroll
  for (int ks = 0; ks < 8; ++ks) {
    short8 A2h = *(const short8*)&hh[m * 264 + ks * 32 + quad * 8];
    short8 A2l = *(const short8*)&hl[m * 264 + ks * 32 + quad * 8];
#pragma unroll
    for (int nt = 0; nt < 8; ++nt) {
      short8 Bh = *(const short8*)(w2h + ((size_t)(nt * 8 + ks) * 64 + lane) * 8);
      short8 Bl = *(const short8*)(w2l + ((size_t)(nt * 8 + ks) * 64 + lane) * 8);
      acc2[nt] = __builtin_amdgcn_mfma_f32_16x16x32_bf16(A2h, Bh, acc2[nt], 0, 0, 0);
      acc2[nt] = __builtin_amdgcn_mfma_f32_16x16x32_bf16(A2l, Bh, acc2[nt], 0, 0, 0);
      acc2[nt] = __builtin_amdgcn_mfma_f32_16x16x32_bf16(A2h, Bl, acc2[nt], 0, 0, 0);
    }
  }

  // residual + bias; LN2 stats per pixel (row = quad*4+r)
  float b2v[8], g2v[8], be2v[8];
#pragma unroll
  for (int nt = 0; nt < 8; ++nt) {
    b2v[nt] = b2[nt * 16 + m];
    g2v[nt] = ln2g[nt * 16 + m];
    be2v[nt] = ln2b[nt * 16 + m];
  }
  float z2[8][4];
  float mean[4], rstd[4];
#pragma unroll
  for (int r = 0; r < 4; ++r) {
    float s = 0.f;
#pragma unroll
    for (int nt = 0; nt < 8; ++nt) {
      float v = acc2[nt][r] + b2v[nt] + zl[(pw + quad * 4 + r) * 132 + nt * 16 + m];
      z2[nt][r] = v;
      s += v;
    }
    s += __shfl_xor(s, 1, 64); s += __shfl_xor(s, 2, 64);
    s += __shfl_xor(s, 4, 64); s += __shfl_xor(s, 8, 64);
    mean[r] = s * (1.0f / 128.0f);
    float vv = 0.f;
#pragma unroll
    for (int nt = 0; nt < 8; ++nt) { float d = z2[nt][r] - mean[r]; vv += d * d; }
    vv += __shfl_xor(vv, 1, 64); vv += __shfl_xor(vv, 2, 64);
    vv += __shfl_xor(vv, 4, 64); vv += __shfl_xor(vv, 8, 64);
    rstd[r] = rsqrtf(vv * (1.0f / 128.0f) + 1e-5f);
  }

  __syncthreads();   // all hdn reads done before zo overwrites the region
  float* zo = (float*)&hdnh[0][0];   // zo[d][pixel], 128 x 66 floats = 33792 B
#pragma unroll
  for (int nt = 0; nt < 8; ++nt)
#pragma unroll
    for (int r = 0; r < 4; ++r) {
      float v = (z2[nt][r] - mean[r]) * rstd[r] * g2v[nt] + be2v[nt];
      zo[(nt * 16 + m) * 66 + pw + quad * 4 + r] = v;
    }
  __syncthreads();

  // coalesced transposed store: out[b][d][p]
  int bb2 = row0 / P_;
  int p0 = row0 - bb2 * P_;
#pragma unroll
  for (int it = 0; it < 8; ++it) {
    int d = (t >> 4) + it * 16;
    int pq = (t & 15) * 4;
    float4 v4 = *(float4*)&zo[d * 66 + pq];
    *(float4*)(out + (size_t)bb2 * DIM_ * P_ + (size_t)d * P_ + p0 + pq) = v4;
  }
}

extern "C" void kernel_launch(void* const* d_in, const int* in_sizes, int n_in,
                              void* d_out, int out_size, void* d_ws, size_t ws_size,
                              hipStream_t stream) {
  const float* feature = (const float*)d_in[0];
  const float* I_src   = (const float*)d_in[1];
  const float* I_tar   = (const float*)d_in[2];
  const float* E       = (const float*)d_in[3];
  const float* dis     = (const float*)d_in[4];
  const float* nrm     = (const float*)d_in[5];
  const float* conv_w  = (const float*)d_in[6];
  const float* bn_g    = (const float*)d_in[7];
  const float* bn_b    = (const float*)d_in[8];
  const float* bn_m    = (const float*)d_in[9];
  const float* bn_v    = (const float*)d_in[10];
  const float* ln1g    = (const float*)d_in[11];
  const float* ln1b    = (const float*)d_in[12];
  const float* ln2g    = (const float*)d_in[13];
  const float* ln2b    = (const float*)d_in[14];
  const float* w1      = (const float*)d_in[15];
  const float* b1      = (const float*)d_in[16];
  const float* w2      = (const float*)d_in[17];
  const float* b2      = (const float*)d_in[18];
  float* out = (float*)d_out;

  float* wsf   = (float*)d_ws;
  float* bns   = wsf;                 // 128
  float* bnb   = wsf + 128;           // 128
  float* val_t = wsf + 256;           // B*N*P*DIM = 17,301,504 floats
  float* zln   = val_t + (size_t)B_ * N_ * P_ * DIM_;   // B*P*DIM floats
  Samp*  samp  = (Samp*)(zln + (size_t)B_ * P_ * DIM_); // 12*P structs (32B each)
  short* w1h   = (short*)(samp + (size_t)B_ * N_ * P_); // 32768 shorts each
  short* w1l   = w1h + 32768;
  short* w2h   = w1l + 32768;
  short* w2l   = w2h + 32768;

  hipLaunchKernelGGL(uv_kernel, dim3(B_ * N_), dim3(256), 0, stream,
                     I_src, I_tar, E, dis, nrm, bn_g, bn_b, bn_m, bn_v, samp, bns, bnb);
  hipLaunchKernelGGL(wprep_kernel, dim3(128), dim3(64), 0, stream,
                     w1, w2, w1h, w1l, w2h, w2l);
  hipLaunchKernelGGL(conv_kernel, dim3(P_ / 64, B_ * N_), dim3(256), 0, stream,
                     feature, conv_w, bns, bnb, val_t);
  hipLaunchKernelGGL(attn_kernel, dim3(B_ * P_ / 4), dim3(256), 0, stream,
                     val_t, samp, ln1g, ln1b, zln);
  hipLaunchKernelGGL(mlp_kernel, dim3(B_ * P_ / 64), dim3(256), 0, stream,
                     zln, w1h, w1l, w2h, w2l, b1, b2, ln2g, ln2b, out);
}

// Round 6
// 246.455 us; speedup vs baseline: 1.5248x; 1.0886x over previous
//
#include <hip/hip_runtime.h>
#include <cstdint>
#include <cstddef>

#define B_   2
#define N_   6
#define FD_  128
#define DIM_ 128
#define H_   64
#define W_   176
#define P_   (H_*W_)      // 11264
#define IMGW 704.0
#define IMGH 256.0

struct __align__(16) Samp { float wx, wy; int o00, o01; int o10, o11; int valid, pad; };

typedef __attribute__((ext_vector_type(8))) short short8;
typedef __attribute__((ext_vector_type(4))) float f32x4;

__device__ __forceinline__ float wave_sum(float v) {
#pragma unroll
  for (int off = 32; off > 0; off >>= 1) v += __shfl_xor(v, off, 64);
  return v;
}

__device__ __forceinline__ unsigned short f2bf(float f) {
  unsigned int u = __float_as_uint(f);
  unsigned int r = (u + 0x7fffu + ((u >> 16) & 1u)) >> 16;
  return (unsigned short)r;
}
__device__ __forceinline__ float bf2f(unsigned short s) {
  return __uint_as_float(((unsigned int)s) << 16);
}

// ---------------- Kernel A: fp64 homography -> sample descriptors; BN fold ----------------
__global__ __launch_bounds__(256) void uv_kernel(const float* __restrict__ I_src, const float* __restrict__ I_tar_inv,
                           const float* __restrict__ E, const float* __restrict__ dis,
                           const float* __restrict__ nrm,
                           const float* __restrict__ bn_g, const float* __restrict__ bn_b,
                           const float* __restrict__ bn_m, const float* __restrict__ bn_v,
                           Samp* __restrict__ samp, float* __restrict__ bns, float* __restrict__ bnb) {
  int bn = blockIdx.x;            // 0..11
  int bb = bn / N_;
  if (bn == 0 && threadIdx.x < FD_) {
    int t = threadIdx.x;
    float inv = 1.0f / sqrtf(bn_v[t] + 1e-5f);
    float sc = bn_g[t] * inv;
    bns[t] = sc;
    bnb[t] = bn_b[t] - bn_m[t] * sc;
  }
  const float* Ep = E + bn * 16;
  double R[9], T[3];
#pragma unroll
  for (int i = 0; i < 3; ++i) {
#pragma unroll
    for (int j = 0; j < 3; ++j) R[i*3+j] = (double)Ep[i*4+j];
    T[i] = (double)Ep[i*4+3];
  }
  double dd = (double)dis[bb];
  double M[9];
#pragma unroll
  for (int i = 0; i < 3; ++i)
#pragma unroll
    for (int j = 0; j < 3; ++j)
      M[i*3+j] = R[i*3+j] - T[i] * (double)nrm[bb*3+j] / dd;
  const float* Is = I_src + bn * 9;
  double A[9];
#pragma unroll
  for (int i = 0; i < 3; ++i)
#pragma unroll
    for (int j = 0; j < 3; ++j)
      A[i*3+j] = (double)Is[i*3+0]*M[0+j] + (double)Is[i*3+1]*M[3+j] + (double)Is[i*3+2]*M[6+j];
  const float* It = I_tar_inv + bb * 9;
  double Hm[9];
#pragma unroll
  for (int i = 0; i < 3; ++i)
#pragma unroll
    for (int j = 0; j < 3; ++j)
      Hm[i*3+j] = A[i*3+0]*(double)It[0+j] + A[i*3+1]*(double)It[3+j] + A[i*3+2]*(double)It[6+j];

  const double dx = 1.0 / (double)(W_ - 1);
  const double dy = 1.0 / (double)(H_ - 1);
  for (int p = threadIdx.x; p < P_; p += 256) {
    int ii = p / W_;
    int jj = p - ii * W_;
    double xs = (jj == W_ - 1) ? 1.0 : (double)jj * dx;   // np.linspace exact endpoint
    double ys = (ii == H_ - 1) ? 1.0 : (double)ii * dy;
    double px = xs * IMGW;
    double py = ys * IMGH;
    double hx = Hm[0]*px + Hm[1]*py + Hm[2];
    double hy = Hm[3]*px + Hm[4]*py + Hm[5];
    double hz = Hm[6]*px + Hm[7]*py + Hm[8];
    double u = ((hx / hz) / IMGW) * (double)W_;
    double v = ((hy / hz) / IMGH) * (double)H_;
    double x0 = floor(u), y0 = floor(v);
    bool valid = (u >= 0.0) && (u <= (double)(W_ - 1)) && (v >= 0.0) && (v <= (double)(H_ - 1));
    int x0i = min(max((int)x0, 0), W_ - 1);
    int x1i = min(x0i + 1, W_ - 1);
    int y0i = min(max((int)y0, 0), H_ - 1);
    int y1i = min(y0i + 1, H_ - 1);
    Samp s;
    s.wx = (float)(u - x0);
    s.wy = (float)(v - y0);
    s.o00 = (y0i * W_ + x0i) * DIM_;
    s.o01 = (y0i * W_ + x1i) * DIM_;
    s.o10 = (y1i * W_ + x0i) * DIM_;
    s.o11 = (y1i * W_ + x1i) * DIM_;
    s.valid = valid ? 1 : 0;
    s.pad = 0;
    samp[(size_t)bn * P_ + p] = s;
  }
}

// ---------------- Kernel A2: pre-swizzle MLP weights into MFMA B-frag layout (hi/lo bf16) ----------------
__global__ __launch_bounds__(64) void wprep_kernel(const float* __restrict__ w1, const float* __restrict__ w2,
    short* __restrict__ w1h, short* __restrict__ w1l,
    short* __restrict__ w2h, short* __restrict__ w2l) {
  int l = threadIdx.x;
  int f = blockIdx.x;     // 0..127
  if (f < 64) {
    int nt = f >> 2, ks = f & 3;
    int n = nt * 16 + (l & 15);
    int kb = ks * 32 + (l >> 4) * 8;
#pragma unroll
    for (int j = 0; j < 8; ++j) {
      float v = w1[(size_t)(kb + j) * 256 + n];
      unsigned short h = f2bf(v);
      w1h[((size_t)f * 64 + l) * 8 + j] = (short)h;
      w1l[((size_t)f * 64 + l) * 8 + j] = (short)f2bf(v - bf2f(h));
    }
  } else {
    int g = f - 64;
    int nt = g >> 3, ks = g & 7;
    int n = nt * 16 + (l & 15);
    int kb = ks * 32 + (l >> 4) * 8;
#pragma unroll
    for (int j = 0; j < 8; ++j) {
      float v = w2[(size_t)(kb + j) * 128 + n];
      unsigned short h = f2bf(v);
      w2h[((size_t)g * 64 + l) * 8 + j] = (short)h;
      w2l[((size_t)g * 64 + l) * 8 + j] = (short)f2bf(v - bf2f(h));
    }
  }
}

// ---------------- Kernel B: BN+ReLU+1x1 conv as bf16 MFMA (hi/lo split X) -> val_t[bn][p][o] ----------------
__global__ __launch_bounds__(256) void conv_kernel(const float* __restrict__ feature,
    const float* __restrict__ conv_w, const float* __restrict__ bns_g, const float* __restrict__ bnb_g,
    float* __restrict__ val_t) {
  __shared__ __align__(16) short w_lds[128 * 136];  // 34816 B
  __shared__ __align__(16) short xhi[128 * 66];     // 16896 B
  __shared__ __align__(16) short xlo[128 * 66];     // 16896 B
  __shared__ float bns_s[FD_], bnb_s[FD_];
  int t = threadIdx.x;

#pragma unroll
  for (int k = 0; k < 16; ++k) {
    int f4 = t + 256 * k;
    int o  = f4 >> 5;
    int c4 = (f4 & 31) * 4;
    float4 w = *(const float4*)(conv_w + (size_t)f4 * 4);
    short* dst = &w_lds[o * 136 + c4];
    dst[0] = (short)f2bf(w.x); dst[1] = (short)f2bf(w.y);
    dst[2] = (short)f2bf(w.z); dst[3] = (short)f2bf(w.w);
  }
  if (t < FD_) { bns_s[t] = bns_g[t]; bnb_s[t] = bnb_g[t]; }
  __syncthreads();

  int bn = blockIdx.y;
  int p0 = blockIdx.x * 64;
  const float* fb = feature + (size_t)bn * FD_ * P_ + p0;

#pragma unroll
  for (int k = 0; k < 8; ++k) {
    int f4 = t + 256 * k;
    int c  = f4 >> 4;
    int pq = (f4 & 15) * 4;
    float4 x = *(const float4*)(fb + (size_t)c * P_ + pq);
    float s = bns_s[c], o = bnb_s[c];
    float v0 = fmaxf(x.x * s + o, 0.f);
    float v1 = fmaxf(x.y * s + o, 0.f);
    float v2 = fmaxf(x.z * s + o, 0.f);
    float v3 = fmaxf(x.w * s + o, 0.f);
    unsigned short h0 = f2bf(v0), h1 = f2bf(v1), h2 = f2bf(v2), h3 = f2bf(v3);
    unsigned short l0 = f2bf(v0 - bf2f(h0)), l1 = f2bf(v1 - bf2f(h1));
    unsigned short l2 = f2bf(v2 - bf2f(h2)), l3 = f2bf(v3 - bf2f(h3));
    short* dh = &xhi[c * 66 + pq];
    short* dl = &xlo[c * 66 + pq];
    dh[0] = (short)h0; dh[1] = (short)h1; dh[2] = (short)h2; dh[3] = (short)h3;
    dl[0] = (short)l0; dl[1] = (short)l1; dl[2] = (short)l2; dl[3] = (short)l3;
  }
  __syncthreads();

  int lane = t & 63, wv = t >> 6;
  int m = lane & 15, quad = lane >> 4;
  int pw = wv * 16;

  short8 Ah[4], Al[4];
#pragma unroll
  for (int ks = 0; ks < 4; ++ks) {
#pragma unroll
    for (int j = 0; j < 8; ++j) {
      int c = ks * 32 + quad * 8 + j;
      Ah[ks][j] = xhi[c * 66 + pw + m];
      Al[ks][j] = xlo[c * 66 + pw + m];
    }
  }

  f32x4 acc[8];
#pragma unroll
  for (int ot = 0; ot < 8; ++ot) {
    f32x4 a = {0.f, 0.f, 0.f, 0.f};
#pragma unroll
    for (int ks = 0; ks < 4; ++ks) {
      short8 Bv = *(const short8*)&w_lds[(ot * 16 + m) * 136 + ks * 32 + quad * 8];
      a = __builtin_amdgcn_mfma_f32_16x16x32_bf16(Ah[ks], Bv, a, 0, 0, 0);
      a = __builtin_amdgcn_mfma_f32_16x16x32_bf16(Al[ks], Bv, a, 0, 0, 0);
    }
    acc[ot] = a;
  }

  float* vb = val_t + ((size_t)bn * P_ + p0 + pw + quad * 4) * DIM_ + m;
#pragma unroll
  for (int ot = 0; ot < 8; ++ot)
#pragma unroll
    for (int r = 0; r < 4; ++r)
      vb[(size_t)r * DIM_ + ot * 16] = acc[ot][r];
}

// ---------------- Kernel C: warp-per-point bilinear attention + LN1 ----------------
__global__ __launch_bounds__(256) void attn_kernel(const float* __restrict__ val_t,
    const Samp* __restrict__ samp,
    const float* __restrict__ ln1g, const float* __restrict__ ln1b,
    float* __restrict__ zln) {
  int lane = threadIdx.x & 63;
  int wv = threadIdx.x >> 6;
  int pt = blockIdx.x * 4 + wv;
  if (pt >= B_ * P_) return;
  int bb = pt / P_;
  int p = pt - bb * P_;
  int d0 = lane << 1;

  float2 q = *(const float2*)(val_t + ((size_t)(bb * N_) * P_ + p) * DIM_ + d0);
  float qss = wave_sum(q.x * q.x + q.y * q.y);
  float qinv = 1.0f / fmaxf(sqrtf(qss), 1e-12f);
  float qn0 = q.x * qinv, qn1 = q.y * qinv;

  float dots[N_], vs0[N_], vs1[N_];
#pragma unroll
  for (int n = 0; n < N_; ++n) {
    Samp s = samp[(size_t)(bb * N_ + n) * P_ + p];
    const float* base = val_t + (size_t)(bb * N_ + n) * P_ * DIM_ + d0;
    float2 g00 = *(const float2*)(base + s.o00);
    float2 g01 = *(const float2*)(base + s.o01);
    float2 g10 = *(const float2*)(base + s.o10);
    float2 g11 = *(const float2*)(base + s.o11);
    float wx = s.wx, wy = s.wy;
    float w00 = (1.0f - wx) * (1.0f - wy), w01 = wx * (1.0f - wy);
    float w10 = (1.0f - wx) * wy,          w11 = wx * wy;
    float v0 = g00.x*w00 + g01.x*w01 + g10.x*w10 + g11.x*w11;
    float v1 = g00.y*w00 + g01.y*w01 + g10.y*w10 + g11.y*w11;
    float ss = wave_sum(v0 * v0 + v1 * v1);
    float kinv = 1.0f / fmaxf(sqrtf(ss), 1e-12f);
    float dt = wave_sum(qn0 * (v0 * kinv) + qn1 * (v1 * kinv));
    dots[n] = s.valid ? dt : 0.0f;
    vs0[n] = v0; vs1[n] = v1;
  }
  float mx = dots[0];
#pragma unroll
  for (int n = 1; n < N_; ++n) mx = fmaxf(mx, dots[n]);
  float es[N_], den = 0.f;
#pragma unroll
  for (int n = 0; n < N_; ++n) { es[n] = expf(dots[n] - mx); den += es[n]; }
  float dinv = 1.0f / den;
  float z0 = q.x, z1 = q.y;
#pragma unroll
  for (int n = 0; n < N_; ++n) { float a = es[n] * dinv; z0 += a * vs0[n]; z1 += a * vs1[n]; }
  float mean = wave_sum(z0 + z1) * (1.0f / DIM_);
  float c0 = z0 - mean, c1 = z1 - mean;
  float var = wave_sum(c0 * c0 + c1 * c1) * (1.0f / DIM_);
  float rstd = rsqrtf(var + 1e-5f);
  float o0 = c0 * rstd * ln1g[d0]     + ln1b[d0];
  float o1 = c1 * rstd * ln1g[d0 + 1] + ln1b[d0 + 1];
  *(float2*)(zln + (size_t)pt * DIM_ + d0) = make_float2(o0, o1);
}

// ---------------- Kernel D: MLP via bf16 MFMA (3-term hi/lo) + LN2 + transposed output ----------------
// Round-4 proven skeleton (4 waves x 16 px, write-once/read-once hdn), with phase-unioned LDS:
// phase1 zl (33.8 KB) -> barrier -> phase2 hdnh/hdnl overlay (67.6 KB) -> barrier -> phase3 zo (34.8 KB).
// Residual is pulled into registers before zl is released. 67.6 KB static LDS -> 2 blocks/CU.
__global__ __launch_bounds__(256) void mlp_kernel(const float* __restrict__ zln,
    const short* __restrict__ w1h, const short* __restrict__ w1l,
    const short* __restrict__ w2h, const short* __restrict__ w2l,
    const float* __restrict__ b1, const float* __restrict__ b2,
    const float* __restrict__ ln2g, const float* __restrict__ ln2b,
    float* __restrict__ out) {
  __shared__ __align__(16) char smem[67584];
  int t = threadIdx.x;
  int row0 = blockIdx.x * 64;

  // ---- phase 1: zl tile (64 x 128, stride 132) ----
  float* zl = (float*)smem;
#pragma unroll
  for (int k = 0; k < 8; ++k) {
    int idx = t + 256 * k;        // 0..2047 float4s
    int r = idx >> 5, c4 = (idx & 31) * 4;
    *(float4*)&zl[r * 132 + c4] = *(const float4*)(zln + (size_t)(row0 + r) * DIM_ + c4);
  }
  __syncthreads();

  int lane = t & 63, wv = t >> 6, m = lane & 15, quad = lane >> 4;
  int pw = wv * 16;

  // A1 frags (hi/lo) from zl
  short8 A1h[4], A1l[4];
#pragma unroll
  for (int ks = 0; ks < 4; ++ks) {
    const float* zr = &zl[(pw + m) * 132 + ks * 32 + quad * 8];
#pragma unroll
    for (int j = 0; j < 8; ++j) {
      float v = zr[j];
      unsigned short h = f2bf(v);
      A1h[ks][j] = (short)h;
      A1l[ks][j] = (short)f2bf(v - bf2f(h));
    }
  }
  // residual to registers (C-layout positions this lane will own)
  float res[8][4];
#pragma unroll
  for (int nt = 0; nt < 8; ++nt)
#pragma unroll
    for (int r = 0; r < 4; ++r)
      res[nt][r] = zl[(pw + quad * 4 + r) * 132 + nt * 16 + m];

  float b1v[16];
#pragma unroll
  for (int nt = 0; nt < 16; ++nt) b1v[nt] = b1[nt * 16 + m];
  float b2v[8], g2v[8], be2v[8];
#pragma unroll
  for (int nt = 0; nt < 8; ++nt) {
    b2v[nt] = b2[nt * 16 + m];
    g2v[nt] = ln2g[nt * 16 + m];
    be2v[nt] = ln2b[nt * 16 + m];
  }
  __syncthreads();   // zl dead; smem becomes hdn

  // ---- phase 2: hdn staging (per-wave 16 x 264 shorts, hi then lo halves of smem) ----
  short* hh = (short*)smem + wv * (16 * 264);
  short* hl = (short*)(smem + 33792) + wv * (16 * 264);

  // GEMM1 + GELU + hdn store (wave-local region; write-once)
#pragma unroll
  for (int nt = 0; nt < 16; ++nt) {
    f32x4 a = {0.f, 0.f, 0.f, 0.f};
#pragma unroll
    for (int ks = 0; ks < 4; ++ks) {
      short8 Bh = *(const short8*)(w1h + ((size_t)(nt * 4 + ks) * 64 + lane) * 8);
      short8 Bl = *(const short8*)(w1l + ((size_t)(nt * 4 + ks) * 64 + lane) * 8);
      a = __builtin_amdgcn_mfma_f32_16x16x32_bf16(A1h[ks], Bh, a, 0, 0, 0);
      a = __builtin_amdgcn_mfma_f32_16x16x32_bf16(A1l[ks], Bh, a, 0, 0, 0);
      a = __builtin_amdgcn_mfma_f32_16x16x32_bf16(A1h[ks], Bl, a, 0, 0, 0);
    }
#pragma unroll
    for (int r = 0; r < 4; ++r) {
      float hv = a[r] + b1v[nt];
      float g = 0.5f * hv * (1.0f + erff(hv * 0.70710678118654752f));
      unsigned short gh = f2bf(g);
      int addr = (quad * 4 + r) * 264 + nt * 16 + m;
      hh[addr] = (short)gh;
      hl[addr] = (short)f2bf(g - bf2f(gh));
    }
  }

  // GEMM2: A from hdn (own wave region), B from global w2 frags
  f32x4 acc2[8];
#pragma unroll
  for (int nt = 0; nt < 8; ++nt) acc2[nt] = (f32x4){0.f, 0.f, 0.f, 0.f};
#pragma unroll
  for (int ks = 0; ks < 8; ++ks) {
    short8 A2h = *(const short8*)&hh[m * 264 + ks * 32 + quad * 8];
    short8 A2l = *(const short8*)&hl[m * 264 + ks * 32 + quad * 8];
#pragma unroll
    for (int nt = 0; nt < 8; ++nt) {
      short8 Bh = *(const short8*)(w2h + ((size_t)(nt * 8 + ks) * 64 + lane) * 8);
      short8 Bl = *(const short8*)(w2l + ((size_t)(nt * 8 + ks) * 64 + lane) * 8);
      acc2[nt] = __builtin_amdgcn_mfma_f32_16x16x32_bf16(A2h, Bh, acc2[nt], 0, 0, 0);
      acc2[nt] = __builtin_amdgcn_mfma_f32_16x16x32_bf16(A2l, Bh, acc2[nt], 0, 0, 0);
      acc2[nt] = __builtin_amdgcn_mfma_f32_16x16x32_bf16(A2h, Bl, acc2[nt], 0, 0, 0);
    }
  }

  // bias + residual + LN2 (per-pixel stats via m-group shuffles)
  float z2[8][4], mean[4], rstd[4];
#pragma unroll
  for (int r = 0; r < 4; ++r) {
    float s = 0.f;
#pragma unroll
    for (int nt = 0; nt < 8; ++nt) {
      float v = acc2[nt][r] + b2v[nt] + res[nt][r];
      z2[nt][r] = v;
      s += v;
    }
    s += __shfl_xor(s, 1, 64); s += __shfl_xor(s, 2, 64);
    s += __shfl_xor(s, 4, 64); s += __shfl_xor(s, 8, 64);
    mean[r] = s * (1.0f / 128.0f);
    float vv = 0.f;
#pragma unroll
    for (int nt = 0; nt < 8; ++nt) { float d = z2[nt][r] - mean[r]; vv += d * d; }
    vv += __shfl_xor(vv, 1, 64); vv += __shfl_xor(vv, 2, 64);
    vv += __shfl_xor(vv, 4, 64); vv += __shfl_xor(vv, 8, 64);
    rstd[r] = rsqrtf(vv * (1.0f / 128.0f) + 1e-5f);
  }

  __syncthreads();   // all hdn reads done before zo overlay
  // ---- phase 3: zo transpose buffer (128 x 68 floats, aligned) ----
  float* zo = (float*)smem;
#pragma unroll
  for (int nt = 0; nt < 8; ++nt)
#pragma unroll
    for (int r = 0; r < 4; ++r) {
      float v = (z2[nt][r] - mean[r]) * rstd[r] * g2v[nt] + be2v[nt];
      zo[(nt * 16 + m) * 68 + pw + quad * 4 + r] = v;
    }
  __syncthreads();

  // coalesced transposed store: out[b][d][p]
  int bb2 = row0 / P_;
  int p0 = row0 - bb2 * P_;
#pragma unroll
  for (int it = 0; it < 8; ++it) {
    int d = it * 16 + (t >> 4);
    int pq = (t & 15) * 4;
    float4 v4 = *(float4*)&zo[d * 68 + pq];
    *(float4*)(out + (size_t)bb2 * DIM_ * P_ + (size_t)d * P_ + p0 + pq) = v4;
  }
}

extern "C" void kernel_launch(void* const* d_in, const int* in_sizes, int n_in,
                              void* d_out, int out_size, void* d_ws, size_t ws_size,
                              hipStream_t stream) {
  const float* feature = (const float*)d_in[0];
  const float* I_src   = (const float*)d_in[1];
  const float* I_tar   = (const float*)d_in[2];
  const float* E       = (const float*)d_in[3];
  const float* dis     = (const float*)d_in[4];
  const float* nrm     = (const float*)d_in[5];
  const float* conv_w  = (const float*)d_in[6];
  const float* bn_g    = (const float*)d_in[7];
  const float* bn_b    = (const float*)d_in[8];
  const float* bn_m    = (const float*)d_in[9];
  const float* bn_v    = (const float*)d_in[10];
  const float* ln1g    = (const float*)d_in[11];
  const float* ln1b    = (const float*)d_in[12];
  const float* ln2g    = (const float*)d_in[13];
  const float* ln2b    = (const float*)d_in[14];
  const float* w1      = (const float*)d_in[15];
  const float* b1      = (const float*)d_in[16];
  const float* w2      = (const float*)d_in[17];
  const float* b2      = (const float*)d_in[18];
  float* out = (float*)d_out;

  float* wsf   = (float*)d_ws;
  float* bns   = wsf;                 // 128
  float* bnb   = wsf + 128;           // 128
  float* val_t = wsf + 256;           // B*N*P*DIM floats
  float* zln   = val_t + (size_t)B_ * N_ * P_ * DIM_;   // B*P*DIM floats
  Samp*  samp  = (Samp*)(zln + (size_t)B_ * P_ * DIM_); // 12*P structs (32B each)
  short* w1h   = (short*)(samp + (size_t)B_ * N_ * P_); // 32768 shorts each
  short* w1l   = w1h + 32768;
  short* w2h   = w1l + 32768;
  short* w2l   = w2h + 32768;

  hipLaunchKernelGGL(uv_kernel, dim3(B_ * N_), dim3(256), 0, stream,
                     I_src, I_tar, E, dis, nrm, bn_g, bn_b, bn_m, bn_v, samp, bns, bnb);
  hipLaunchKernelGGL(wprep_kernel, dim3(128), dim3(64), 0, stream,
                     w1, w2, w1h, w1l, w2h, w2l);
  hipLaunchKernelGGL(conv_kernel, dim3(P_ / 64, B_ * N_), dim3(256), 0, stream,
                     feature, conv_w, bns, bnb, val_t);
  hipLaunchKernelGGL(attn_kernel, dim3(B_ * P_ / 4), dim3(256), 0, stream,
                     val_t, samp, ln1g, ln1b, zln);
  hipLaunchKernelGGL(mlp_kernel, dim3(B_ * P_ / 64), dim3(256), 0, stream,
                     zln, w1h, w1l, w2h, w2l, b1, b2, ln2g, ln2b, out);
}